// Round 5
// baseline (572.897 us; speedup 1.0000x reference)
//
#include <hip/hip_runtime.h>
#include <hip/hip_bf16.h>

// N=51200, E=800000 (E%16==0), G=128, DIN=DE=DOUT=64, DG=128
//   AB[i] (bf16, quad-major permuted layout):
//     A-half elem (q*16 + mt*4 + r) = (h_node[i] @ W1[0:64,:] + b1)[mt*16+q*4+r]
//     B-half elem (64 + q*16 + mt*4 + r) = (h_node[i] @ W1[64:128,:])[mt*16+q*4+r]
//   msg_e  = relu(relu(A'[src]+B[dst]+h_edge@W1c) @ W2 + b2)
//   gg[g]  = sum_{e: graph(dst_e)=g} msg_e            (block partials + k_reduce)
//   out[g] = relu(concat(u[g], gg[g]@Wn + cnt_g*bn) @ Wg + bg)
// MFMA 16x16x32 bf16, feats = M rows, edges/nodes = N cols.
//   C/D: col=lane&15, row=quad*4+reg ; A/B frag: [free=lane&15][k=quad*8+j]

typedef __attribute__((ext_vector_type(8))) short short8;
typedef __attribute__((ext_vector_type(4))) float f32x4;

#define WB() __builtin_amdgcn_wave_barrier()
#define IMIN(a,b) ((a)<(b)?(a):(b))

__device__ inline unsigned short f2bfu(float x) {
    unsigned u = __builtin_bit_cast(unsigned, x);
    u += 0x7fffu + ((u >> 16) & 1u);          // round-to-nearest-even
    return (unsigned short)(u >> 16);
}
__device__ inline short f2bf(float x) { return (short)f2bfu(x); }
__device__ inline unsigned pk2(float a, float b) {
    return (unsigned)f2bfu(a) | ((unsigned)f2bfu(b) << 16);
}
__device__ inline short8 cvt8(f32x4 a, f32x4 b) {
    union { unsigned u[4]; short8 s; } r;
    r.u[0] = pk2(a[0], a[1]); r.u[1] = pk2(a[2], a[3]);
    r.u[2] = pk2(b[0], b[1]); r.u[3] = pk2(b[2], b[3]);
    return r.s;
}
__device__ inline f32x4 bf4f(unsigned px, unsigned py) {  // 4 packed bf16 -> f32x4
    f32x4 r;
    r[0] = __builtin_bit_cast(float, px << 16);
    r[1] = __builtin_bit_cast(float, px & 0xffff0000u);
    r[2] = __builtin_bit_cast(float, py << 16);
    r[3] = __builtin_bit_cast(float, py & 0xffff0000u);
    return r;
}

// ---------------------------------------------------------------------------
// K0: AB (bf16, permuted) via MFMA; b1 folded into the A half.
__global__ __launch_bounds__(256) void k_node_mfma(
    const float* __restrict__ h_node, const float* __restrict__ W1,
    const float* __restrict__ b1, unsigned short* __restrict__ AB, int N)
{
    const int lane = threadIdx.x & 63;
    const int quad = lane >> 4, col = lane & 15;

    short8 wf[2][8];
    for (int ks = 0; ks < 2; ++ks)
        for (int mt = 0; mt < 8; ++mt) {
            const int feat = mt * 16 + col;
            const float* Wc = W1 + (size_t)((feat >> 6) * 64) * 64 + (feat & 63);
            short8 f;
            for (int j = 0; j < 8; ++j) f[j] = f2bf(Wc[(size_t)(ks * 32 + quad * 8 + j) * 64]);
            wf[ks][mt] = f;
        }
    f32x4 binit[8];
    for (int mt = 0; mt < 8; ++mt) {
        if (mt < 4) binit[mt] = *(const f32x4*)(b1 + mt * 16 + quad * 4);
        else        binit[mt] = (f32x4){0.f, 0.f, 0.f, 0.f};
    }

    const int wid = (blockIdx.x * blockDim.x + threadIdx.x) >> 6;
    const int nw  = (gridDim.x * blockDim.x) >> 6;
    const int ntiles = N >> 4;
    for (int t = wid; t < ntiles; t += nw) {
        const int node = t * 16 + col;
        const float* xr = h_node + (size_t)node * 64 + quad * 8;
        f32x4 x0 = *(const f32x4*)(xr);
        f32x4 x1 = *(const f32x4*)(xr + 4);
        f32x4 x2 = *(const f32x4*)(xr + 32);
        f32x4 x3 = *(const f32x4*)(xr + 36);
        short8 xb0 = cvt8(x0, x1), xb1 = cvt8(x2, x3);

        f32x4 acc[8];
#pragma unroll
        for (int mt = 0; mt < 8; ++mt) acc[mt] = binit[mt];
#pragma unroll
        for (int mt = 0; mt < 8; ++mt)
            acc[mt] = __builtin_amdgcn_mfma_f32_16x16x32_bf16(wf[0][mt], xb0, acc[mt], 0, 0, 0);
#pragma unroll
        for (int mt = 0; mt < 8; ++mt)
            acc[mt] = __builtin_amdgcn_mfma_f32_16x16x32_bf16(wf[1][mt], xb1, acc[mt], 0, 0, 0);

        // permuted store: feat mt*16+quad*4+r  ->  half*64 + quad*16 + (mt%4)*4 + r
        unsigned short* orow = AB + (size_t)node * 128 + quad * 16;
#pragma unroll
        for (int mt = 0; mt < 8; ++mt) {
            uint2 p;
            p.x = pk2(acc[mt][0], acc[mt][1]);
            p.y = pk2(acc[mt][2], acc[mt][3]);
            *(uint2*)(orow + (mt >> 2) * 64 + (mt & 3) * 4) = p;
        }
    }
}

// ---------------------------------------------------------------------------
// K1: fused edge MLP + per-graph scatter; per-block partial output (no global atomics).
__global__ __launch_bounds__(256) void k_edge_mfma(
    const float* __restrict__ h_edge, const unsigned short* __restrict__ AB,
    const float* __restrict__ W1, const float* __restrict__ W2,
    const float* __restrict__ b2,
    const int* __restrict__ src, const int* __restrict__ dst,
    const int* __restrict__ ngid,
    float* __restrict__ gg_part, int E)
{
    __shared__ float sgg[128 * 65];        // 33.3 KB per-graph accumulator (pad 65)
    __shared__ short tlds[4][16 * 72];     // per-wave layer1->layer2 tile
    const int wave = threadIdx.x >> 6, lane = threadIdx.x & 63;
    const int quad = lane >> 4, col = lane & 15;

    for (int i = threadIdx.x; i < 128 * 65; i += 256) sgg[i] = 0.f;

    short8 w1f[2][4], w2f[2][4];
    for (int ks = 0; ks < 2; ++ks)
        for (int mt = 0; mt < 4; ++mt) {
            const int feat = mt * 16 + col;
            short8 f1, f2;
            for (int j = 0; j < 8; ++j) {
                const int k = ks * 32 + quad * 8 + j;
                f1[j] = f2bf(W1[(size_t)(128 + k) * 64 + feat]);
                f2[j] = f2bf(W2[(size_t)k * 64 + feat]);
            }
            w1f[ks][mt] = f1; w2f[ks][mt] = f2;
        }
    f32x4 bb2[4];
#pragma unroll
    for (int mt = 0; mt < 4; ++mt) bb2[mt] = *(const f32x4*)(b2 + mt * 16 + quad * 4);
    __syncthreads();

    short* tl = tlds[wave];
    const int wid = (blockIdx.x * blockDim.x + threadIdx.x) >> 6;
    const int nwv = (gridDim.x * blockDim.x) >> 6;
    const int ntiles = E >> 4;
    const int per = (ntiles + nwv - 1) / nwv;
    const int t0 = wid * per;
    const int t1 = IMIN(t0 + per, ntiles);

#define LOADI(tt, sx, dx) { const int ee = (tt) * 16 + col; sx = src[ee]; dx = dst[ee]; }
#define LOADD(sx, dx, tt, gv, ap, bp, xv) { \
    gv = ngid[dx]; \
    const uint4* a_ = (const uint4*)(AB + (size_t)(sx) * 128 + quad * 16); \
    const uint4* c_ = (const uint4*)(AB + (size_t)(dx) * 128 + 64 + quad * 16); \
    ap[0] = a_[0]; ap[1] = a_[1]; \
    bp[0] = c_[0]; bp[1] = c_[1]; \
    const f32x4* x_ = (const f32x4*)(h_edge + (size_t)((tt) * 16 + col) * 64 + quad * 8); \
    xv[0] = __builtin_nontemporal_load(x_); \
    xv[1] = __builtin_nontemporal_load(x_ + 1); \
    xv[2] = __builtin_nontemporal_load(x_ + 8); \
    xv[3] = __builtin_nontemporal_load(x_ + 9); }

#define COMPUTE(gv, ap, bp, xv) { \
    short8 xb0 = cvt8(xv[0], xv[1]), xb1 = cvt8(xv[2], xv[3]); \
    f32x4 acc[4]; \
    acc[0] = bf4f(ap[0].x, ap[0].y) + bf4f(bp[0].x, bp[0].y); \
    acc[1] = bf4f(ap[0].z, ap[0].w) + bf4f(bp[0].z, bp[0].w); \
    acc[2] = bf4f(ap[1].x, ap[1].y) + bf4f(bp[1].x, bp[1].y); \
    acc[3] = bf4f(ap[1].z, ap[1].w) + bf4f(bp[1].z, bp[1].w); \
    _Pragma("unroll") \
    for (int mt = 0; mt < 4; ++mt) \
        acc[mt] = __builtin_amdgcn_mfma_f32_16x16x32_bf16(w1f[0][mt], xb0, acc[mt], 0, 0, 0); \
    _Pragma("unroll") \
    for (int mt = 0; mt < 4; ++mt) \
        acc[mt] = __builtin_amdgcn_mfma_f32_16x16x32_bf16(w1f[1][mt], xb1, acc[mt], 0, 0, 0); \
    _Pragma("unroll") \
    for (int mt = 0; mt < 4; ++mt) { \
        uint2 p; \
        p.x = pk2(fmaxf(acc[mt][0], 0.f), fmaxf(acc[mt][1], 0.f)); \
        p.y = pk2(fmaxf(acc[mt][2], 0.f), fmaxf(acc[mt][3], 0.f)); \
        *(uint2*)&tl[col * 72 + mt * 16 + quad * 4] = p; \
    } \
    WB(); \
    short8 tb0 = *(const short8*)&tl[col * 72 + quad * 8]; \
    short8 tb1 = *(const short8*)&tl[col * 72 + 32 + quad * 8]; \
    f32x4 ac2[4]; \
    _Pragma("unroll") \
    for (int mt = 0; mt < 4; ++mt) ac2[mt] = bb2[mt]; \
    _Pragma("unroll") \
    for (int mt = 0; mt < 4; ++mt) \
        ac2[mt] = __builtin_amdgcn_mfma_f32_16x16x32_bf16(w2f[0][mt], tb0, ac2[mt], 0, 0, 0); \
    _Pragma("unroll") \
    for (int mt = 0; mt < 4; ++mt) \
        ac2[mt] = __builtin_amdgcn_mfma_f32_16x16x32_bf16(w2f[1][mt], tb1, ac2[mt], 0, 0, 0); \
    WB(); \
    float* sg_ = sgg + gv * 65; \
    _Pragma("unroll") \
    for (int mt = 0; mt < 4; ++mt) { \
        _Pragma("unroll") \
        for (int r = 0; r < 4; ++r) \
            atomicAdd(&sg_[mt * 16 + quad * 4 + r], fmaxf(ac2[mt][r], 0.f)); \
    } }

    if (t0 < t1) {
        int s0i, d0i, s1i, d1i, g0, g1;
        uint4 a0[2], b0[2], a1[2], b1p[2];
        f32x4 x0[4], x1[4];
        LOADI(t0, s0i, d0i);
        LOADI(IMIN(t0 + 1, t1 - 1), s1i, d1i);
        LOADD(s0i, d0i, t0, g0, a0, b0, x0);
        LOADI(IMIN(t0 + 2, t1 - 1), s0i, d0i);
        LOADD(s1i, d1i, IMIN(t0 + 1, t1 - 1), g1, a1, b1p, x1);
        LOADI(IMIN(t0 + 3, t1 - 1), s1i, d1i);
        for (int t = t0; t < t1; t += 2) {
            COMPUTE(g0, a0, b0, x0);                       // tile t
            LOADD(s0i, d0i, IMIN(t + 2, t1 - 1), g0, a0, b0, x0);
            LOADI(IMIN(t + 4, t1 - 1), s0i, d0i);
            if (t + 1 < t1) {
                COMPUTE(g1, a1, b1p, x1);                  // tile t+1
                LOADD(s1i, d1i, IMIN(t + 3, t1 - 1), g1, a1, b1p, x1);
                LOADI(IMIN(t + 5, t1 - 1), s1i, d1i);
            }
        }
    }
    __syncthreads();

    // non-atomic per-block partial dump (coalesced); k_reduce folds them.
    float* part = gg_part + (size_t)blockIdx.x * 8192;
    for (int i = threadIdx.x; i < 8192; i += 256)
        part[i] = sgg[(i >> 6) * 65 + (i & 63)];
#undef LOADI
#undef LOADD
#undef COMPUTE
}

// ---------------------------------------------------------------------------
// K1b: fold P block partials into gg. 8 slices per slot + one HW atomic each.
__global__ __launch_bounds__(256) void k_reduce(
    const float* __restrict__ gp, float* __restrict__ gg, int P)
{
    const int gid = blockIdx.x * 256 + threadIdx.x;   // 65536 threads
    const int j = gid & 8191, s = gid >> 13;          // slice 0..7
    float a0 = 0.f, a1 = 0.f;
    int b = s;
    for (; b + 16 <= P; b += 16) {
        a0 += gp[(size_t)b * 8192 + j];
        a1 += gp[(size_t)(b + 8) * 8192 + j];
    }
    for (; b < P; b += 8) a0 += gp[(size_t)b * 8192 + j];
    unsafeAtomicAdd(&gg[j], a0 + a1);
}

// ---------------------------------------------------------------------------
// K2: per-graph epilogue; cnt via binary search on sorted node_graph_id.
__global__ __launch_bounds__(128) void k_final(
    const float* __restrict__ u, const float* __restrict__ gg,
    const int* __restrict__ ngid, int N,
    const float* __restrict__ Wn, const float* __restrict__ bn,
    const float* __restrict__ Wg, const float* __restrict__ bg,
    float* __restrict__ out)
{
    const int g = blockIdx.x, t = threadIdx.x;
    __shared__ float sgg[64];
    __shared__ float sn[64];
    __shared__ int scnt;
    if (t == 0) {
        int lo = 0, hi = N;
        while (lo < hi) { int m = (lo + hi) >> 1; if (ngid[m] < g) lo = m + 1; else hi = m; }
        const int a = lo;
        lo = 0; hi = N;
        while (lo < hi) { int m = (lo + hi) >> 1; if (ngid[m] < g + 1) lo = m + 1; else hi = m; }
        scnt = lo - a;
    }
    if (t < 64) sgg[t] = gg[g * 64 + t];
    __syncthreads();
    if (t < 64) {
        float acc = bn[t] * (float)scnt;
        for (int k = 0; k < 64; ++k)
            acc = fmaf(sgg[k], Wn[k * 64 + t], acc);
        sn[t] = acc;
    }
    __syncthreads();
    float acc = bg[t];
    for (int k = 0; k < 128; ++k)
        acc = fmaf(u[g * 128 + k], Wg[k * 128 + t], acc);
    for (int k = 0; k < 64; ++k)
        acc = fmaf(sn[k], Wg[(128 + k) * 128 + t], acc);
    out[g * 128 + t] = fmaxf(acc, 0.f);
}

// ---------------------------------------------------------------------------
extern "C" void kernel_launch(void* const* d_in, const int* in_sizes, int n_in,
                              void* d_out, int out_size, void* d_ws, size_t ws_size,
                              hipStream_t stream)
{
    const float* h_node = (const float*)d_in[0];
    const float* h_edge = (const float*)d_in[1];
    const float* u      = (const float*)d_in[2];
    const float* W1     = (const float*)d_in[3];
    const float* b1     = (const float*)d_in[4];
    const float* W2     = (const float*)d_in[5];
    const float* b2     = (const float*)d_in[6];
    const float* Wn     = (const float*)d_in[7];
    const float* bn     = (const float*)d_in[8];
    const float* Wg     = (const float*)d_in[9];
    const float* bg     = (const float*)d_in[10];
    const int*   src    = (const int*)d_in[11];
    const int*   dst    = (const int*)d_in[12];
    const int*   ngid   = (const int*)d_in[13];

    const int N = in_sizes[0] / 64;
    const int E = in_sizes[1] / 64;
    const int G = in_sizes[2] / 128;

    unsigned short* AB = (unsigned short*)d_ws;            // N*128 bf16 (13.1 MB)
    float* gg      = (float*)(AB + (size_t)N * 128);       // G*64 f32 (32 KB)
    float* gg_part = gg + (size_t)G * 64;                  // P * G*64 f32

    const size_t fixed = (size_t)N * 128 * 2 + (size_t)G * 64 * 4;
    int P = (int)IMIN((size_t)768, (ws_size - fixed) / ((size_t)G * 64 * 4));
    if (P < 1) P = 1;

    (void)hipMemsetAsync(gg, 0, (size_t)G * 64 * sizeof(float), stream);

    k_node_mfma<<<400, 256, 0, stream>>>(h_node, W1, b1, AB, N);
    k_edge_mfma<<<P, 256, 0, stream>>>(h_edge, AB, W1, W2, b2, src, dst, ngid, gg_part, E);
    k_reduce<<<256, 256, 0, stream>>>(gg_part, gg, P);
    k_final<<<G, 128, 0, stream>>>(u, gg, ngid, N, Wn, bn, Wg, bg, (float*)d_out);
}

// Round 6
// 397.353 us; speedup vs baseline: 1.4418x; 1.4418x over previous
//
#include <hip/hip_runtime.h>
#include <hip/hip_bf16.h>

// N=51200, E=800000 (E%16==0), G=128, DIN=DE=DOUT=64, DG=128
// Pipeline:
//   k_node:    AB[i] = bf16(h_node[i] @ W1[0:128,:] + [b1;0])  (quad-permuted rows)
//   k_hist/k_s1/k_s2/k_s3/k_scatter: counting-sort edges by g = ngid[dst],
//       each graph's range padded to %16 so every 16-edge tile is graph-pure.
//       Sorted slot i: sd[i] = src | dst<<16 (N<65536), eid[i] = orig edge (-1 pad).
//   k_edge:    msg = relu(relu(A'[src]+B[dst]+h_edge@W1c) @ W2 + b2);
//       per-wave REGISTER accumulator racc (graph-pure tiles), flushed on
//       graph change via shfl_xor butterfly + unsafeAtomicAdd into gg[G,64].
//   k_final:   out[g] = relu(concat(u[g], gg[g]@Wn + cnt_g*bn) @ Wg + bg)
// MFMA 16x16x32 bf16: C/D col=lane&15,row=quad*4+reg; A/B frag [free=lane&15][k=quad*8+j]

typedef __attribute__((ext_vector_type(8))) short short8;
typedef __attribute__((ext_vector_type(4))) float f32x4;

#define WB() __builtin_amdgcn_wave_barrier()
#define IMIN(a,b) ((a)<(b)?(a):(b))

__device__ inline unsigned short f2bfu(float x) {
    unsigned u = __builtin_bit_cast(unsigned, x);
    u += 0x7fffu + ((u >> 16) & 1u);          // RNE
    return (unsigned short)(u >> 16);
}
__device__ inline short f2bf(float x) { return (short)f2bfu(x); }
__device__ inline unsigned pk2(float a, float b) {
    return (unsigned)f2bfu(a) | ((unsigned)f2bfu(b) << 16);
}
__device__ inline short8 cvt8(f32x4 a, f32x4 b) {
    union { unsigned u[4]; short8 s; } r;
    r.u[0] = pk2(a[0], a[1]); r.u[1] = pk2(a[2], a[3]);
    r.u[2] = pk2(b[0], b[1]); r.u[3] = pk2(b[2], b[3]);
    return r.s;
}
__device__ inline f32x4 bf4f(unsigned px, unsigned py) {
    f32x4 r;
    r[0] = __builtin_bit_cast(float, px << 16);
    r[1] = __builtin_bit_cast(float, px & 0xffff0000u);
    r[2] = __builtin_bit_cast(float, py << 16);
    r[3] = __builtin_bit_cast(float, py & 0xffff0000u);
    return r;
}

// ---------------------------------------------------------------------------
// K0: AB (bf16, quad-permuted) via MFMA; b1 folded into A half.
__global__ __launch_bounds__(256) void k_node_mfma(
    const float* __restrict__ h_node, const float* __restrict__ W1,
    const float* __restrict__ b1, unsigned short* __restrict__ AB, int N)
{
    const int lane = threadIdx.x & 63;
    const int quad = lane >> 4, col = lane & 15;

    short8 wf[2][8];
    for (int ks = 0; ks < 2; ++ks)
        for (int mt = 0; mt < 8; ++mt) {
            const int feat = mt * 16 + col;
            const float* Wc = W1 + (size_t)((feat >> 6) * 64) * 64 + (feat & 63);
            short8 f;
            for (int j = 0; j < 8; ++j) f[j] = f2bf(Wc[(size_t)(ks * 32 + quad * 8 + j) * 64]);
            wf[ks][mt] = f;
        }
    f32x4 binit[8];
    for (int mt = 0; mt < 8; ++mt) {
        if (mt < 4) binit[mt] = *(const f32x4*)(b1 + mt * 16 + quad * 4);
        else        binit[mt] = (f32x4){0.f, 0.f, 0.f, 0.f};
    }

    const int wid = (blockIdx.x * blockDim.x + threadIdx.x) >> 6;
    const int nw  = (gridDim.x * blockDim.x) >> 6;
    const int ntiles = N >> 4;
    for (int t = wid; t < ntiles; t += nw) {
        const int node = t * 16 + col;
        const float* xr = h_node + (size_t)node * 64 + quad * 8;
        f32x4 x0 = *(const f32x4*)(xr);
        f32x4 x1 = *(const f32x4*)(xr + 4);
        f32x4 x2 = *(const f32x4*)(xr + 32);
        f32x4 x3 = *(const f32x4*)(xr + 36);
        short8 xb0 = cvt8(x0, x1), xb1 = cvt8(x2, x3);

        f32x4 acc[8];
#pragma unroll
        for (int mt = 0; mt < 8; ++mt) acc[mt] = binit[mt];
#pragma unroll
        for (int mt = 0; mt < 8; ++mt)
            acc[mt] = __builtin_amdgcn_mfma_f32_16x16x32_bf16(wf[0][mt], xb0, acc[mt], 0, 0, 0);
#pragma unroll
        for (int mt = 0; mt < 8; ++mt)
            acc[mt] = __builtin_amdgcn_mfma_f32_16x16x32_bf16(wf[1][mt], xb1, acc[mt], 0, 0, 0);

        unsigned short* orow = AB + (size_t)node * 128 + quad * 16;
#pragma unroll
        for (int mt = 0; mt < 8; ++mt) {
            uint2 p;
            p.x = pk2(acc[mt][0], acc[mt][1]);
            p.y = pk2(acc[mt][2], acc[mt][3]);
            *(uint2*)(orow + (mt >> 2) * 64 + (mt & 3) * 4) = p;
        }
    }
}

// ---------------------------------------------------------------------------
// Sort pass 1: per-block per-graph counts, transposed layout cntT[g*256+b].
__global__ __launch_bounds__(256) void k_hist(
    const int* __restrict__ dst, const int* __restrict__ ngid,
    int* __restrict__ cntT, int E)
{
    __shared__ int h[128];
    if (threadIdx.x < 128) h[threadIdx.x] = 0;
    __syncthreads();
    for (int e = blockIdx.x * 256 + threadIdx.x; e < E; e += 256 * 256)
        atomicAdd(&h[ngid[dst[e]]], 1);
    __syncthreads();
    if (threadIdx.x < 128) cntT[threadIdx.x * 256 + blockIdx.x] = h[threadIdx.x];
}

// Sort pass 2a: per-graph exclusive scan over the 256 block counts.
__global__ __launch_bounds__(256) void k_s1(
    const int* __restrict__ cntT, int* __restrict__ relBase, int* __restrict__ padTot)
{
    __shared__ int sc[256];
    const int g = blockIdx.x, t = threadIdx.x;
    const int c = cntT[g * 256 + t];
    sc[t] = c; __syncthreads();
    for (int off = 1; off < 256; off <<= 1) {
        int v = (t >= off) ? sc[t - off] : 0;
        __syncthreads();
        sc[t] += v;
        __syncthreads();
    }
    relBase[g * 256 + t] = sc[t] - c;
    if (t == 0) padTot[g] = (sc[255] + 15) & ~15;
}

// Sort pass 2b: exclusive scan of padded totals -> per-graph base.
__global__ __launch_bounds__(128) void k_s2(
    const int* __restrict__ padTot, int* __restrict__ base)
{
    __shared__ int sc[128];
    const int t = threadIdx.x;
    const int v = padTot[t];
    sc[t] = v; __syncthreads();
    for (int off = 1; off < 128; off <<= 1) {
        int u = (t >= off) ? sc[t - off] : 0;
        __syncthreads();
        sc[t] += u;
        __syncthreads();
    }
    base[t] = sc[t] - v;
}

// Sort pass 2c: tile -> graph map.
__global__ __launch_bounds__(256) void k_s3(
    const int* __restrict__ base, const int* __restrict__ padTot,
    int* __restrict__ tile_g)
{
    const int g = blockIdx.x;
    const int t0 = base[g] >> 4, nt = padTot[g] >> 4;
    for (int i = threadIdx.x; i < nt; i += 256) tile_g[t0 + i] = g;
}

// Sort pass 3: scatter edges into graph-sorted slots.
__global__ __launch_bounds__(256) void k_scatter(
    const int* __restrict__ src, const int* __restrict__ dst,
    const int* __restrict__ ngid,
    const int* __restrict__ relBase, const int* __restrict__ base,
    unsigned* __restrict__ sd, int* __restrict__ eid, int E)
{
    __shared__ int lcnt[128];
    if (threadIdx.x < 128)
        lcnt[threadIdx.x] = relBase[threadIdx.x * 256 + blockIdx.x] + base[threadIdx.x];
    __syncthreads();
    for (int e = blockIdx.x * 256 + threadIdx.x; e < E; e += 256 * 256) {
        const int d = dst[e], g = ngid[d];
        const int pos = atomicAdd(&lcnt[g], 1);
        sd[pos] = (unsigned)src[e] | ((unsigned)d << 16);
        eid[pos] = e;
    }
}

// ---------------------------------------------------------------------------
// flush: butterfly-sum racc over the 16 cols, then HW atomics into gg[g].
__device__ inline void flushacc(float* __restrict__ gg, int g, f32x4* racc,
                                int quad, int col)
{
    if (g < 0) return;
#pragma unroll
    for (int mt = 0; mt < 4; ++mt)
#pragma unroll
        for (int r = 0; r < 4; ++r) {
            float v = racc[mt][r];
            v += __shfl_xor(v, 1);
            v += __shfl_xor(v, 2);
            v += __shfl_xor(v, 4);
            v += __shfl_xor(v, 8);
            racc[mt][r] = v;
        }
    if (col == 0) {
#pragma unroll
        for (int mt = 0; mt < 4; ++mt)
#pragma unroll
            for (int r = 0; r < 4; ++r)
                unsafeAtomicAdd(&gg[g * 64 + mt * 16 + quad * 4 + r], racc[mt][r]);
    }
}

// K1: fused edge MLP, graph-pure tiles, register accumulation.
__global__ __launch_bounds__(256) void k_edge_mfma(
    const float* __restrict__ h_edge, const unsigned short* __restrict__ AB,
    const float* __restrict__ W1, const float* __restrict__ W2,
    const float* __restrict__ b2,
    const unsigned* __restrict__ sd, const int* __restrict__ eid,
    const int* __restrict__ tile_g,
    float* __restrict__ gg, int ntiles)
{
    __shared__ short tlds[4][16 * 72];     // per-wave layer1->layer2 tile (9.2 KB)
    const int wave = threadIdx.x >> 6, lane = threadIdx.x & 63;
    const int quad = lane >> 4, col = lane & 15;

    short8 w1f[2][4], w2f[2][4];
    for (int ks = 0; ks < 2; ++ks)
        for (int mt = 0; mt < 4; ++mt) {
            const int feat = mt * 16 + col;
            short8 f1, f2;
            for (int j = 0; j < 8; ++j) {
                const int k = ks * 32 + quad * 8 + j;
                f1[j] = f2bf(W1[(size_t)(128 + k) * 64 + feat]);
                f2[j] = f2bf(W2[(size_t)k * 64 + feat]);
            }
            w1f[ks][mt] = f1; w2f[ks][mt] = f2;
        }
    f32x4 bb2[4];
#pragma unroll
    for (int mt = 0; mt < 4; ++mt) bb2[mt] = *(const f32x4*)(b2 + mt * 16 + quad * 4);

    short* tl = tlds[wave];
    const int wid = (blockIdx.x * blockDim.x + threadIdx.x) >> 6;
    const int nwv = (gridDim.x * blockDim.x) >> 6;
    const int per = (ntiles + nwv - 1) / nwv;
    const int t0 = wid * per;
    const int t1 = IMIN(t0 + per, ntiles);

    if (t0 >= t1) return;

    f32x4 racc[4];
#pragma unroll
    for (int mt = 0; mt < 4; ++mt) racc[mt] = (f32x4){0.f, 0.f, 0.f, 0.f};
    int curg = -1;

    int ev; unsigned sdv; int gv;
    {   // indices for t0
        const int slot = t0 * 16 + col;
        ev = eid[slot];
        unsigned sv = sd[slot];
        sdv = ev >= 0 ? sv : 0u;
        gv = tile_g[t0];
    }

    for (int t = t0; t < t1; ++t) {
        // ---- issue gathers for current tile
        const int s_ = (int)(sdv & 0xffffu), d_ = (int)(sdv >> 16);
        const int ec = ev >= 0 ? ev : 0;
        const uint4* a_ = (const uint4*)(AB + (size_t)s_ * 128 + quad * 16);
        const uint4* c_ = (const uint4*)(AB + (size_t)d_ * 128 + 64 + quad * 16);
        uint4 ap0 = a_[0], ap1 = a_[1];
        uint4 bp0 = c_[0], bp1 = c_[1];
        const f32x4* x_ = (const f32x4*)(h_edge + (size_t)ec * 64 + quad * 8);
        f32x4 xv0 = __builtin_nontemporal_load(x_);
        f32x4 xv1 = __builtin_nontemporal_load(x_ + 1);
        f32x4 xv2 = __builtin_nontemporal_load(x_ + 8);
        f32x4 xv3 = __builtin_nontemporal_load(x_ + 9);
        const float vm = ev >= 0 ? 1.f : 0.f;

        // ---- prefetch next tile's indices (overlaps gather latency)
        int evn = ev; unsigned sdn = sdv; int gvn = gv;
        if (t + 1 < t1) {
            const int slot = (t + 1) * 16 + col;
            evn = eid[slot];
            unsigned sv = sd[slot];
            sdn = evn >= 0 ? sv : 0u;
            gvn = tile_g[t + 1];
        }

        // ---- flush on graph change (wave-uniform)
        if (gv != curg) {
            flushacc(gg, curg, racc, quad, col);
            curg = gv;
#pragma unroll
            for (int mt = 0; mt < 4; ++mt) racc[mt] = (f32x4){0.f, 0.f, 0.f, 0.f};
        }

        // ---- layer 1
        short8 xb0 = cvt8(xv0, xv1), xb1 = cvt8(xv2, xv3);
        f32x4 acc[4];
        acc[0] = bf4f(ap0.x, ap0.y) + bf4f(bp0.x, bp0.y);
        acc[1] = bf4f(ap0.z, ap0.w) + bf4f(bp0.z, bp0.w);
        acc[2] = bf4f(ap1.x, ap1.y) + bf4f(bp1.x, bp1.y);
        acc[3] = bf4f(ap1.z, ap1.w) + bf4f(bp1.z, bp1.w);
#pragma unroll
        for (int mt = 0; mt < 4; ++mt)
            acc[mt] = __builtin_amdgcn_mfma_f32_16x16x32_bf16(w1f[0][mt], xb0, acc[mt], 0, 0, 0);
#pragma unroll
        for (int mt = 0; mt < 4; ++mt)
            acc[mt] = __builtin_amdgcn_mfma_f32_16x16x32_bf16(w1f[1][mt], xb1, acc[mt], 0, 0, 0);

        // ---- relu -> bf16 -> LDS C->A layout transform
#pragma unroll
        for (int mt = 0; mt < 4; ++mt) {
            uint2 p;
            p.x = pk2(fmaxf(acc[mt][0], 0.f), fmaxf(acc[mt][1], 0.f));
            p.y = pk2(fmaxf(acc[mt][2], 0.f), fmaxf(acc[mt][3], 0.f));
            *(uint2*)&tl[col * 72 + mt * 16 + quad * 4] = p;
        }
        WB();
        short8 tb0 = *(const short8*)&tl[col * 72 + quad * 8];
        short8 tb1 = *(const short8*)&tl[col * 72 + 32 + quad * 8];

        // ---- layer 2
        f32x4 ac2[4];
#pragma unroll
        for (int mt = 0; mt < 4; ++mt) ac2[mt] = bb2[mt];
#pragma unroll
        for (int mt = 0; mt < 4; ++mt)
            ac2[mt] = __builtin_amdgcn_mfma_f32_16x16x32_bf16(w2f[0][mt], tb0, ac2[mt], 0, 0, 0);
#pragma unroll
        for (int mt = 0; mt < 4; ++mt)
            ac2[mt] = __builtin_amdgcn_mfma_f32_16x16x32_bf16(w2f[1][mt], tb1, ac2[mt], 0, 0, 0);
        WB();

        // ---- relu + masked accumulate into registers (no scatter!)
#pragma unroll
        for (int mt = 0; mt < 4; ++mt)
#pragma unroll
            for (int r = 0; r < 4; ++r)
                racc[mt][r] = fmaf(fmaxf(ac2[mt][r], 0.f), vm, racc[mt][r]);

        ev = evn; sdv = sdn; gv = gvn;
    }
    flushacc(gg, curg, racc, quad, col);
}

// ---------------------------------------------------------------------------
// K2: per-graph epilogue; cnt via binary search on sorted node_graph_id.
__global__ __launch_bounds__(128) void k_final(
    const float* __restrict__ u, const float* __restrict__ gg,
    const int* __restrict__ ngid, int N,
    const float* __restrict__ Wn, const float* __restrict__ bn,
    const float* __restrict__ Wg, const float* __restrict__ bg,
    float* __restrict__ out)
{
    const int g = blockIdx.x, t = threadIdx.x;
    __shared__ float sgg[64];
    __shared__ float sn[64];
    __shared__ int scnt;
    if (t == 0) {
        int lo = 0, hi = N;
        while (lo < hi) { int m = (lo + hi) >> 1; if (ngid[m] < g) lo = m + 1; else hi = m; }
        const int a = lo;
        lo = 0; hi = N;
        while (lo < hi) { int m = (lo + hi) >> 1; if (ngid[m] < g + 1) lo = m + 1; else hi = m; }
        scnt = lo - a;
    }
    if (t < 64) sgg[t] = gg[g * 64 + t];
    __syncthreads();
    if (t < 64) {
        float acc = bn[t] * (float)scnt;
        for (int k = 0; k < 64; ++k)
            acc = fmaf(sgg[k], Wn[k * 64 + t], acc);
        sn[t] = acc;
    }
    __syncthreads();
    float acc = bg[t];
    for (int k = 0; k < 128; ++k)
        acc = fmaf(u[g * 128 + k], Wg[k * 128 + t], acc);
    for (int k = 0; k < 64; ++k)
        acc = fmaf(sn[k], Wg[(128 + k) * 128 + t], acc);
    out[g * 128 + t] = fmaxf(acc, 0.f);
}

// ---------------------------------------------------------------------------
extern "C" void kernel_launch(void* const* d_in, const int* in_sizes, int n_in,
                              void* d_out, int out_size, void* d_ws, size_t ws_size,
                              hipStream_t stream)
{
    const float* h_node = (const float*)d_in[0];
    const float* h_edge = (const float*)d_in[1];
    const float* u      = (const float*)d_in[2];
    const float* W1     = (const float*)d_in[3];
    const float* b1     = (const float*)d_in[4];
    const float* W2     = (const float*)d_in[5];
    const float* b2     = (const float*)d_in[6];
    const float* Wn     = (const float*)d_in[7];
    const float* bn     = (const float*)d_in[8];
    const float* Wg     = (const float*)d_in[9];
    const float* bg     = (const float*)d_in[10];
    const int*   src    = (const int*)d_in[11];
    const int*   dst    = (const int*)d_in[12];
    const int*   ngid   = (const int*)d_in[13];

    const int N = in_sizes[0] / 64;
    const int E = in_sizes[1] / 64;
    const int G = in_sizes[2] / 128;
    const int T_MAX = E / 16 + G;          // padded tile upper bound (50128)
    const size_t SLOTS = (size_t)T_MAX * 16;

    char* p = (char*)d_ws;
    unsigned short* AB = (unsigned short*)p;  p += (size_t)N * 128 * 2;   // 13.1 MB
    float* gg      = (float*)p;               p += (size_t)G * 64 * 4;    // 32 KB
    int* cntT      = (int*)p;                 p += 128 * 256 * 4;         // 128 KB
    int* relBase   = (int*)p;                 p += 128 * 256 * 4;         // 128 KB
    int* padTot    = (int*)p;                 p += 128 * 4;
    int* baseArr   = (int*)p;                 p += 128 * 4;
    int* tile_g    = (int*)p;                 p += (size_t)T_MAX * 4;     // 200 KB
    unsigned* sdA  = (unsigned*)p;            p += SLOTS * 4;             // 3.2 MB
    int* eidA      = (int*)p;                 /* SLOTS * 4 */             // 3.2 MB

    (void)hipMemsetAsync(gg, 0, (size_t)G * 64 * sizeof(float), stream);
    (void)hipMemsetAsync(tile_g, 0, (size_t)T_MAX * sizeof(int), stream);
    (void)hipMemsetAsync(eidA, 0xFF, SLOTS * sizeof(int), stream);        // -1

    k_node_mfma<<<400, 256, 0, stream>>>(h_node, W1, b1, AB, N);
    k_hist    <<<256, 256, 0, stream>>>(dst, ngid, cntT, E);
    k_s1      <<<128, 256, 0, stream>>>(cntT, relBase, padTot);
    k_s2      <<<1,   128, 0, stream>>>(padTot, baseArr);
    k_s3      <<<128, 256, 0, stream>>>(baseArr, padTot, tile_g);
    k_scatter <<<256, 256, 0, stream>>>(src, dst, ngid, relBase, baseArr, sdA, eidA, E);
    k_edge_mfma<<<1024, 256, 0, stream>>>(h_edge, AB, W1, W2, b2, sdA, eidA, tile_g, gg, T_MAX);
    k_final   <<<G, 128, 0, stream>>>(u, gg, ngid, N, Wn, bn, Wg, bg, (float*)d_out);
}